// Round 3
// baseline (1068.959 us; speedup 1.0000x reference)
//
#include <hip/hip_runtime.h>
#include <cstdio>
#include <cstdint>

#define BB 16
#define HH 48
#define WW 48
#define DD 384
#define NTOK 2304            // HH*WW
#define EPS 1e-5f
#define SZB 28311552u        // BB*NTOK*DD*2 bytes (one bf16 tensor); xlo = xhi + SZB

typedef __attribute__((ext_vector_type(4))) float f32x4;
typedef __attribute__((ext_vector_type(8))) short bf16x8;
typedef __attribute__((ext_vector_type(4))) short bf16x4;

__device__ __forceinline__ unsigned short f2bf(float f) {
  uint32_t u = __float_as_uint(f);
  uint32_t r = (u + 0x7FFFu + ((u >> 16) & 1u)) >> 16;
  return (unsigned short)r;
}
__device__ __forceinline__ float bf2f(short s) {
  return __uint_as_float(((uint32_t)(unsigned short)s) << 16);
}

typedef __attribute__((address_space(3))) uint32_t lds_u32;
typedef __attribute__((address_space(1))) const uint32_t glob_u32;
__device__ __forceinline__ void gload_lds16(const void* g, void* l) {
  __builtin_amdgcn_global_load_lds((glob_u32*)g, (lds_u32*)l, 16, 0, 0);
}

// ---------------- K1: x + posenc -> hi/lo bf16 ----------------
__global__ void k_prep(const float* __restrict__ x, const float* __restrict__ Wp,
                       const float* __restrict__ bp, short* __restrict__ xhi,
                       short* __restrict__ xlo) {
  size_t e = ((size_t)blockIdx.x * 256 + threadIdx.x) * 4;
  int d = (int)(e % DD);
  int n = (int)((e / DD) % NTOK);
  float fh = (float)(n / WW), fw = (float)(n % WW);
  f32x4 v = *(const f32x4*)(x + e);
  bf16x4 hv, lv;
#pragma unroll
  for (int j = 0; j < 4; ++j) {
    float pe = fh * Wp[d + j] + fw * Wp[DD + d + j] + bp[d + j];
    float val = v[j] + pe;
    unsigned short hb = f2bf(val);
    hv[j] = (short)hb;
    lv[j] = (short)f2bf(val - bf2f((short)hb));
  }
  *(bf16x4*)(xhi + e) = hv;
  *(bf16x4*)(xlo + e) = lv;
}

// ---------------- K1T: per-batch transpose of hi -> xhiT[b][d][n] ----------------
__global__ void k_transpose(const short* __restrict__ xhi, short* __restrict__ xhiT) {
  __shared__ __attribute__((aligned(16))) short t[64 * 72];
  int tid = threadIdx.x;
  int d0 = blockIdx.x * 64, n0 = blockIdx.y * 64, b = blockIdx.z;
  const short* src = xhi + ((size_t)(b * NTOK + n0)) * DD + d0;
#pragma unroll
  for (int it = 0; it < 2; ++it) {
    int ci = tid + it * 256;
    int r = ci >> 3, c8 = ci & 7;
    *(bf16x8*)(&t[r * 72 + c8 * 8]) = *(const bf16x8*)(src + (size_t)r * DD + c8 * 8);
  }
  __syncthreads();
  short* dst = xhiT + ((size_t)b * DD + d0) * NTOK + n0;
#pragma unroll
  for (int it = 0; it < 2; ++it) {
    int ci = tid + it * 256;
    int dr = ci >> 3, m8 = ci & 7;
    bf16x8 v;
#pragma unroll
    for (int j = 0; j < 8; ++j) v[j] = t[(m8 * 8 + j) * 72 + dr];
    *(bf16x8*)(dst + (size_t)dr * NTOK + m8 * 8) = v;
  }
}

// ---------------- KW: W1^T, W2^T bf16 ----------------
__global__ void k_wprep(const float* __restrict__ W1, const float* __restrict__ W2,
                        short* __restrict__ w1t, short* __restrict__ w2t) {
  int idx = blockIdx.x * 256 + threadIdx.x;
  int r = idx / DD, c = idx % DD;
  w1t[c * DD + r] = (short)f2bf(W1[idx]);
  w2t[c * DD + r] = (short)f2bf(W2[idx]);
}

// ---------------- K2: flash attention (16-row K halves, paired; deep prefetch) ----
#define NPAIR 72             // NTOK / 32

__global__ __launch_bounds__(256, 2)
void k_attn(const short* __restrict__ xhi, const short* __restrict__ xlo,
            const short* __restrict__ xhiT, short* __restrict__ aout) {
  // kb0/kb1: 16 K-rows each: hi region [0,12288) + lo region [12288,24576),
  //          row stride 768B, byte-swizzle col ^= (row&7)<<4 (conflict-free A-reads).
  // sv: V^T pair tile [384 d][32 m] bf16, 64B rows (analytically bank-balanced).
  // sp: per-wave P [16 q][32 m] bf16, row stride 80B (16B-aligned, bank-balanced).
  __shared__ __attribute__((aligned(16))) char kb0[24576];
  __shared__ __attribute__((aligned(16))) char kb1[24576];
  __shared__ __attribute__((aligned(16))) char sv[24576];
  __shared__ __attribute__((aligned(16))) char sp[5120];
  const int tid = threadIdx.x;
  const int lane = tid & 63, wave = tid >> 6;
  const int ln15 = lane & 15, lg = lane >> 4;
  // XCD-aware swizzle: 2 batches per XCD (72 blocks/XCD) for K/V L2 locality.
  const int lid = blockIdx.x;
  const int xcd = lid & 7, slot = lid >> 3;       // slot 0..71
  const int b = 2 * xcd + (slot >= 36 ? 1 : 0);
  const int qt = (slot >= 36) ? slot - 36 : slot;
  const int q0 = qt * 64;
  const int swz = (ln15 & 7) << 4;

  // staging source offsets (dest linear per wave-chunk; K source pre-swizzled)
  uint32_t kvo[6], vvo[6];
#pragma unroll
  for (int j = 0; j < 6; ++j) {
    int d = wave * 6144 + j * 1024 + lane * 16;   // dest byte in 24KB tile
    int rg = d >= 12288 ? 1 : 0;                  // 0=hi, 1=lo
    int rem = d - rg * 12288;
    int row = rem / 768;
    int col = rem - row * 768;
    int scol = col ^ ((row & 7) << 4);
    kvo[j] = (uint32_t)(row * 768 + scol) + (rg ? SZB : 0u);
    vvo[j] = (uint32_t)((d >> 6) * (NTOK * 2) + (d & 63));
  }
  const char* kbp = (const char*)xhi + (size_t)b * NTOK * 768;
  const char* vbp = (const char*)xhiT + (size_t)b * DD * NTOK * 2;
  char* k0u = kb0 + wave * 6144;
  char* k1u = kb1 + wave * 6144;
  char* svu = sv + wave * 6144;
  char* spw = sp + wave * 1280;

  // Q hi fragments resident; Q lo streamed (short live range keeps VGPR low)
  bf16x8 qh[12];
  {
    const short* qp = xhi + ((size_t)b * NTOK + q0 + wave * 16 + ln15) * DD + lg * 8;
#pragma unroll
    for (int kf = 0; kf < 12; ++kf) qh[kf] = *(const bf16x8*)(qp + kf * 32);
  }
  const short* qlp = xlo + ((size_t)b * NTOK + q0 + wave * 16 + ln15) * DD + lg * 8;

  f32x4 o[24];
#pragma unroll
  for (int i = 0; i < 24; ++i) o[i] = f32x4{0.f, 0.f, 0.f, 0.f};
  float m1 = -INFINITY, l1 = 0.0f;

  // prologue: stage kb0(pair 0)
#pragma unroll
  for (int j = 0; j < 6; ++j) gload_lds16(kbp + kvo[j], k0u + j * 1024);

#pragma unroll 1
  for (int p = 0; p < NPAIR; ++p) {
    __syncthreads();   // barA: kb0(p) ready (issued 1 phase ago); kb1/sv WAR safe
    // issue kb1(p) + V(p) — drained at barB, hidden under even-QK
#pragma unroll
    for (int j = 0; j < 6; ++j) gload_lds16(kbp + 12288 + kvo[j], k1u + j * 1024);
#pragma unroll
    for (int j = 0; j < 6; ++j) gload_lds16(vbp + vvo[j], svu + j * 1024);

    // ---- even QK (kb0): 3 independent accumulator chains ----
    f32x4 shh = f32x4{0.f,0.f,0.f,0.f}, shl = shh, slh = shh;
    __builtin_amdgcn_s_setprio(1);
#pragma unroll
    for (int kf = 0; kf < 12; ++kf) {
      bf16x8 ql = *(const bf16x8*)(qlp + kf * 32);
      const int ca = (kf * 64 + lg * 16) ^ swz;
      bf16x8 ah = *(const bf16x8*)(kb0 + ln15 * 768 + ca);
      bf16x8 al = *(const bf16x8*)(kb0 + 12288 + ln15 * 768 + ca);
      shh = __builtin_amdgcn_mfma_f32_16x16x32_bf16(ah, qh[kf], shh, 0, 0, 0);
      shl = __builtin_amdgcn_mfma_f32_16x16x32_bf16(ah, ql, shl, 0, 0, 0);
      slh = __builtin_amdgcn_mfma_f32_16x16x32_bf16(al, qh[kf], slh, 0, 0, 0);
    }
    __builtin_amdgcn_s_setprio(0);
    f32x4 sE;
#pragma unroll
    for (int r = 0; r < 4; ++r) sE[r] = shh[r] + shl[r] + slh[r];

    __syncthreads();   // barB: kb1(p) + V(p) ready; kb0 consumed
    // issue kb0(p+1) — drained at next barA, hidden under odd-QK+softmax+PV
    if (p + 1 < NPAIR) {
#pragma unroll
      for (int j = 0; j < 6; ++j) gload_lds16(kbp + 24576 + kvo[j], k0u + j * 1024);
    }

    // ---- odd QK (kb1) ----
    shh = f32x4{0.f,0.f,0.f,0.f}; shl = shh; slh = shh;
    __builtin_amdgcn_s_setprio(1);
#pragma unroll
    for (int kf = 0; kf < 12; ++kf) {
      bf16x8 ql = *(const bf16x8*)(qlp + kf * 32);
      const int ca = (kf * 64 + lg * 16) ^ swz;
      bf16x8 ah = *(const bf16x8*)(kb1 + ln15 * 768 + ca);
      bf16x8 al = *(const bf16x8*)(kb1 + 12288 + ln15 * 768 + ca);
      shh = __builtin_amdgcn_mfma_f32_16x16x32_bf16(ah, qh[kf], shh, 0, 0, 0);
      shl = __builtin_amdgcn_mfma_f32_16x16x32_bf16(ah, ql, shl, 0, 0, 0);
      slh = __builtin_amdgcn_mfma_f32_16x16x32_bf16(al, qh[kf], slh, 0, 0, 0);
    }
    __builtin_amdgcn_s_setprio(0);
    f32x4 sO;
#pragma unroll
    for (int r = 0; r < 4; ++r) sO[r] = shh[r] + shl[r] + slh[r];

    // ---- one softmax per 32 keys (lane owns q=ln15; m = half*16 + lg*4 + r) ----
    float tmax = -INFINITY;
#pragma unroll
    for (int r = 0; r < 4; ++r) tmax = fmaxf(fmaxf(tmax, sE[r]), sO[r]);
    tmax = fmaxf(tmax, __shfl_xor(tmax, 16));
    tmax = fmaxf(tmax, __shfl_xor(tmax, 32));
    if (__any(tmax - m1 > 8.f)) {          // defer-max
      float mn = fmaxf(m1, tmax);
      float al_ = __expf(m1 - mn);
      float alr[4];
#pragma unroll
      for (int r = 0; r < 4; ++r) alr[r] = __shfl(al_, lg * 4 + r);
#pragma unroll
      for (int ob = 0; ob < 24; ++ob)
#pragma unroll
        for (int r = 0; r < 4; ++r) o[ob][r] *= alr[r];
      l1 *= al_;
      m1 = mn;
    }
    float rs = 0.0f;
    bf16x4 pkE, pkO;
#pragma unroll
    for (int r = 0; r < 4; ++r) {
      float pe = __expf(sE[r] - m1);
      float po = __expf(sO[r] - m1);
      rs += pe + po;
      pkE[r] = (short)f2bf(pe);
      pkO[r] = (short)f2bf(po);
    }
    rs += __shfl_xor(rs, 16);
    rs += __shfl_xor(rs, 32);
    l1 += rs;

    // P write: [q=ln15][m] bf16, stride 80B; even half at +0, odd at +32
    *(bf16x4*)(spw + ln15 * 80 + lg * 8) = pkE;
    *(bf16x4*)(spw + ln15 * 80 + 32 + lg * 8) = pkO;

    // ---- PV: O[q][d] += P[q][0:32] * V[0:32][d] (one k=32 MFMA per 16-d block) ----
    bf16x8 pa = *(const bf16x8*)(spw + ln15 * 80 + lg * 16);
    __builtin_amdgcn_s_setprio(1);
#pragma unroll
    for (int db = 0; db < 24; ++db) {
      bf16x8 vfr = *(const bf16x8*)(sv + (db * 16 + ln15) * 64 + lg * 16);
      o[db] = __builtin_amdgcn_mfma_f32_16x16x32_bf16(pa, vfr, o[db], 0, 0, 0);
    }
    __builtin_amdgcn_s_setprio(0);

    kbp += 24576;   // 32 tokens * 768B
    vbp += 64;      // 32 tokens * 2B
  }

  // epilogue: O /= l, store bf16
  float lr[4];
#pragma unroll
  for (int r = 0; r < 4; ++r) lr[r] = __shfl(l1, lg * 4 + r);
  short* ob_ = aout + ((size_t)b * NTOK + q0 + wave * 16) * DD;
#pragma unroll
  for (int db = 0; db < 24; ++db) {
#pragma unroll
    for (int r = 0; r < 4; ++r) {
      float v = o[db][r] / lr[r];
      ob_[(size_t)(lg * 4 + r) * DD + db * 16 + ln15] = (short)f2bf(v);
    }
  }
}

// ---------------- K3: MLP + residual + LN stats ----------------
__global__ __launch_bounds__(256, 2)
void k_mlp(const short* __restrict__ aout, const short* __restrict__ w1t,
           const short* __restrict__ w2t, const float* __restrict__ b1,
           const float* __restrict__ b2, const short* __restrict__ xhi,
           const short* __restrict__ xlo, float* __restrict__ out,
           float* __restrict__ stats) {
  __shared__ __attribute__((aligned(16))) short hid[4 * 16 * 392];
  __shared__ float redS[4], redQ[4];
  const int tid = threadIdx.x, lane = tid & 63, wave = tid >> 6;
  const int ln15 = lane & 15, lg = lane >> 4;
  const int row0 = blockIdx.x * 64;
  const int bb = row0 / NTOK;

  bf16x8 a[12];
  {
    const short* ap = aout + (size_t)(row0 + wave * 16 + ln15) * DD + lg * 8;
#pragma unroll
    for (int kf = 0; kf < 12; ++kf) a[kf] = *(const bf16x8*)(ap + kf * 32);
  }
  short* hw = &hid[wave * 16 * 392];
#pragma unroll 1
  for (int cb = 0; cb < 24; ++cb) {
    f32x4 acc = f32x4{0.f, 0.f, 0.f, 0.f};
#pragma unroll
    for (int kf = 0; kf < 12; ++kf) {
      bf16x8 wf = *(const bf16x8*)(w1t + (size_t)(cb * 16 + ln15) * DD + kf * 32 + lg * 8);
      acc = __builtin_amdgcn_mfma_f32_16x16x32_bf16(a[kf], wf, acc, 0, 0, 0);
    }
    float bias = b1[cb * 16 + ln15];
#pragma unroll
    for (int r = 0; r < 4; ++r) {
      float v = fmaxf(acc[r] + bias, 0.0f);
      hw[(lg * 4 + r) * 392 + cb * 16 + ln15] = (short)f2bf(v);
    }
  }
  __syncthreads();
  bf16x8 h[12];
#pragma unroll
  for (int kf = 0; kf < 12; ++kf)
    h[kf] = *(const bf16x8*)(&hw[ln15 * 392 + kf * 32 + lg * 8]);
  float ts = 0.f, tq = 0.f;
#pragma unroll 1
  for (int cb = 0; cb < 24; ++cb) {
    f32x4 acc = f32x4{0.f, 0.f, 0.f, 0.f};
#pragma unroll
    for (int kf = 0; kf < 12; ++kf) {
      bf16x8 wf = *(const bf16x8*)(w2t + (size_t)(cb * 16 + ln15) * DD + kf * 32 + lg * 8);
      acc = __builtin_amdgcn_mfma_f32_16x16x32_bf16(h[kf], wf, acc, 0, 0, 0);
    }
    int col = cb * 16 + ln15;
    float bias = b2[col];
#pragma unroll
    for (int r = 0; r < 4; ++r) {
      size_t row = (size_t)row0 + wave * 16 + lg * 4 + r;
      size_t idx = row * DD + col;
      float xv = bf2f(xhi[idx]) + bf2f(xlo[idx]);
      float y = acc[r] + bias + xv;
      out[idx] = y;
      ts += y;
      tq += y * y;
    }
  }
#pragma unroll
  for (int off = 32; off; off >>= 1) {
    ts += __shfl_xor(ts, off);
    tq += __shfl_xor(tq, off);
  }
  if (lane == 0) { redS[wave] = ts; redQ[wave] = tq; }
  __syncthreads();
  if (tid == 0) {
    atomicAdd(&stats[bb], redS[0] + redS[1] + redS[2] + redS[3]);
    atomicAdd(&stats[16 + bb], redQ[0] + redQ[1] + redQ[2] + redQ[3]);
  }
}

// ---------------- K4: LayerNorm ----------------
__global__ void k_ln(float* __restrict__ out, const float* __restrict__ stats) {
  size_t i4 = ((size_t)blockIdx.x * 256 + threadIdx.x) * 4;
  int b = (int)(i4 / ((size_t)NTOK * DD));
  const float cnt = (float)(NTOK * DD);
  float mean = stats[b] / cnt;
  float var = stats[16 + b] / cnt - mean * mean;
  float inv = rsqrtf(var + EPS);
  f32x4 v = *(f32x4*)(out + i4);
#pragma unroll
  for (int j = 0; j < 4; ++j) v[j] = (v[j] - mean) * inv;
  *(f32x4*)(out + i4) = v;
}

// ---------------- launcher ----------------
extern "C" void kernel_launch(void* const* d_in, const int* in_sizes, int n_in,
                              void* d_out, int out_size, void* d_ws, size_t ws_size,
                              hipStream_t stream) {
  const float* x  = (const float*)d_in[0];
  const float* Wp = (const float*)d_in[1];
  const float* bp = (const float*)d_in[2];
  const float* W1 = (const float*)d_in[3];
  const float* b1 = (const float*)d_in[4];
  const float* W2 = (const float*)d_in[5];
  const float* b2 = (const float*)d_in[6];
  float* out = (float*)d_out;

  const size_t SZ = (size_t)SZB;   // 28,311,552 bytes
  char* ws = (char*)d_ws;
  short* xhi  = (short*)ws;
  short* xlo  = (short*)(ws + SZ);      // MUST stay at xhi+SZB (staging offsets rely on it)
  short* xhiT = (short*)(ws + 2 * SZ);
  short* aout = (short*)(ws + 3 * SZ);
  short* w1t  = (short*)(ws + 4 * SZ);
  short* w2t  = (short*)(ws + 4 * SZ + 294912);
  float* stats = (float*)(ws + 4 * SZ + 2 * 294912);
  const size_t need = 4 * SZ + 2 * 294912 + 128;
  if (ws_size < need) {
    fprintf(stderr, "kernel_launch: ws_size %zu < needed %zu\n", ws_size, need);
  }

  k_prep<<<13824, 256, 0, stream>>>(x, Wp, bp, xhi, xlo);
  k_transpose<<<dim3(6, 36, 16), 256, 0, stream>>>(xhi, xhiT);
  k_wprep<<<576, 256, 0, stream>>>(W1, W2, w1t, w2t);
  k_attn<<<576, 256, 0, stream>>>(xhi, xlo, xhiT, aout);
  hipMemsetAsync(stats, 0, 32 * sizeof(float), stream);
  k_mlp<<<576, 256, 0, stream>>>(aout, w1t, w2t, b1, b2, xhi, xlo, out, stats);
  k_ln<<<13824, 256, 0, stream>>>(out, stats);
}